// Round 15
// baseline (58658.319 us; speedup 1.0000x reference)
//
#include <hip/hip_runtime.h>
#include <stdint.h>

#define NBATCH  32
#define NPTS    131072
#define NPOINTS 4096
#define BPB     16           // blocks per batch -> grid = 512 = 2 blocks/CU (16 waves/CU)
#define TPB     512          // threads per block
#define PPT     16           // points per thread = NPTS/BPB/TPB
#define PPB     (NPTS / BPB) // 8192

typedef unsigned long long u64;
typedef unsigned int u32;

#define SLOT_STRIDE 8        // u64s -> 64 B between slots

// Slot (batch, parity, block): word0 = [60:49] it+1 | [48:17] f32 dist bits | [16:0] 131071-gi
//                              word1 = (ybits<<32)|xbits   word2 = zbits
// relaxed payload stores -> release tag store; acquire tag poll -> payload loads.
// Parity double-buffer: slot rewritten only 2 steps later (all pollers passed).
//
// Distance (bit-exact vs harness reference, proven r9):
//   d = fma(dz,dz, fma(dx,dx, dy*dy)), dy^2 separately rounded; min-index ties.
//
// r9-r14 lesson: 50 MB of coords / 32 MB aggregate L2 -> per-step re-reads thrash
// to L3 (~3.5 us/step). Fix: x,y live in 64 KB LDS per block (can't be evicted),
// z+dist = 32 regs/thread (the size the allocator demonstrably keeps resident).
// Per-step global traffic ~ zero; winner coords ride the slots.

__global__ __attribute__((amdgpu_flat_work_group_size(TPB, TPB)))
void fps_kernel(const float* __restrict__ inp, float* __restrict__ out,
                u64* __restrict__ slots)
{
#pragma clang fp contract(off)
    extern __shared__ float2 XY[];   // [PPB] = 8192 float2 = 64 KB dynamic LDS

    const int bid  = blockIdx.x;
    const int b    = bid & 31;   // batch
    const int j    = bid >> 5;   // block-within-batch 0..15
    const int t    = threadIdx.x;
    const int lane = t & 63;
    const int wid  = t >> 6;

    const float* P  = inp + (size_t)b * NPTS * 3;
    float* outP     = out + (size_t)b * NPOINTS * 3;
    float* outIdx   = out + (size_t)NBATCH * NPOINTS * 3 + (size_t)b * NPOINTS;

    const int base = j * PPB;

    float pz[PPT], dist[PPT];    // 32 array VGPRs (allocator keeps this size resident)
#pragma unroll
    for (int k = 0; k < PPT; ++k) {
        const int l = k * TPB + t;
        const float* pp = P + (size_t)(base + l) * 3;
        float x = pp[0], y = pp[1], z = pp[2];
        XY[l] = make_float2(x, y);
        pz[k] = z;
        dist[k] = 1e10f;
    }

    float qx = P[0], qy = P[1], qz = P[2];   // first selected index is 0
    if (j == 0 && t == 0) {
        outP[0] = qx; outP[1] = qy; outP[2] = qz;
        outIdx[0] = 0.0f;                    // whole d_out read back as float32
    }

    u64* myslots = slots + (size_t)b * (2 * BPB * SLOT_STRIDE);

    __shared__ u64 skey[TPB / 64];
    __shared__ float sq[3];

    __syncthreads();   // XY visible to all waves

    for (int it = 0; it < NPOINTS - 1; ++it) {
        // ---- update running min-dist, thread-local argmax (first-max, ascending gi) ----
        float m = -1.0f; int ki = 0;
#pragma unroll
        for (int k = 0; k < PPT; ++k) {
            float2 xy = XY[k * TPB + t];              // ds_read_b64, 2-way bank alias (free)
            float dx = xy.x - qx;
            float dy = xy.y - qy;
            float dz = pz[k] - qz;
            float yy = dy * dy;
            asm("" : "+v"(yy));                       // dy^2 stays separately rounded
            float d  = __builtin_fmaf(dz, dz,
                        __builtin_fmaf(dx, dx, yy));  // reference contraction shape
            float nd = fminf(dist[k], d);
            dist[k] = nd;
            if (nd > m) { m = nd; ki = k; }           // ascending k => ascending gi
        }
        const int gi = base + ki * TPB + t;
        u64 key = ((u64)__float_as_uint(m) << 17) | (u64)(131071 - gi);

        // ---- wave butterfly reduce (max key) ----
#pragma unroll
        for (int s = 1; s < 64; s <<= 1) {
            u64 o = __shfl_xor(key, s, 64);
            if (o > key) key = o;
        }
        if (lane == 0) skey[wid] = key;
        __syncthreads();

        if (wid == 0) {
            // ---- block reduce over 8 wave keys ----
            u64 k2 = (lane < TPB / 64) ? skey[lane] : 0ull;
            u64 kk = k2;
#pragma unroll
            for (int s = 1; s < TPB / 64; s <<= 1) {
                u64 o = __shfl_xor(kk, s, 64);
                if (o > kk) kk = o;
            }
            const int par = it & 1;
            const u64 tag = (u64)(it + 1) << 49;
            if (lane == 0) {
                // publisher loads its own winner's coords once (L2 hit, overlapped
                // across the 16 blocks) so pollers get coords with the poll.
                const int bgi = 131071 - (int)(kk & 0x1FFFF);
                const float* qp = P + (size_t)bgi * 3;
                float wx = qp[0], wy = qp[1], wz = qp[2];
                u64* slot = &myslots[(size_t)(par * BPB + j) * SLOT_STRIDE];
                __hip_atomic_store(&slot[1],
                                   ((u64)__float_as_uint(wy) << 32) | __float_as_uint(wx),
                                   __ATOMIC_RELAXED, __HIP_MEMORY_SCOPE_AGENT);
                __hip_atomic_store(&slot[2], (u64)__float_as_uint(wz),
                                   __ATOMIC_RELAXED, __HIP_MEMORY_SCOPE_AGENT);
                __hip_atomic_store(&slot[0], tag | kk,
                                   __ATOMIC_RELEASE, __HIP_MEMORY_SCOPE_AGENT);
            }
            // ---- poll all BPB slots ----
            u64 tw = 0;
            bool ok = (lane >= BPB);
            int guard = 0;
            while (true) {
                if (!ok) {
                    tw = __hip_atomic_load(&myslots[(size_t)(par * BPB + lane) * SLOT_STRIDE],
                                           __ATOMIC_ACQUIRE, __HIP_MEMORY_SCOPE_AGENT);
                    ok = (tw >> 49) >= (u64)(it + 1);
                }
                if (__all((int)ok)) break;
                if (++guard > (1 << 20)) break;   // hang safeguard
            }
            u64 pxy = 0, pzz = 0, k3 = 0;
            if (lane < BPB) {
                u64* slot = &myslots[(size_t)(par * BPB + lane) * SLOT_STRIDE];
                pxy = __hip_atomic_load(&slot[1], __ATOMIC_RELAXED, __HIP_MEMORY_SCOPE_AGENT);
                pzz = __hip_atomic_load(&slot[2], __ATOMIC_RELAXED, __HIP_MEMORY_SCOPE_AGENT);
                k3  = tw & ((1ull << 49) - 1);
            }
            u64 k3m = k3;
#pragma unroll
            for (int s = 1; s < BPB; s <<= 1) {
                u64 o = __shfl_xor(k3m, s, 64);
                if (o > k3m) k3m = o;
            }
            int w3 = __ffsll(__ballot(k3 == k3m && lane < BPB)) - 1;
            u64 wxy = __shfl(pxy, w3, 64);
            u64 wzz = __shfl(pzz, w3, 64);
            if (lane == 0) {
                float nqx = __uint_as_float((u32)wxy);
                float nqy = __uint_as_float((u32)(wxy >> 32));
                float nqz = __uint_as_float((u32)wzz);
                sq[0] = nqx; sq[1] = nqy; sq[2] = nqz;
                if (j == 0) {
                    float* o3 = outP + (size_t)(it + 1) * 3;
                    o3[0] = nqx; o3[1] = nqy; o3[2] = nqz;
                    outIdx[it + 1] = (float)(131071 - (int)(k3m & 0x1FFFF));
                }
            }
        }
        __syncthreads();
        qx = sq[0]; qy = sq[1]; qz = sq[2];
    }
}

extern "C" void kernel_launch(void* const* d_in, const int* in_sizes, int n_in,
                              void* d_out, int out_size, void* d_ws, size_t ws_size,
                              hipStream_t stream)
{
    const float* inp = (const float*)d_in[0];
    float* outp      = (float*)d_out;
    u64* slots       = (u64*)d_ws;

    hipMemsetAsync(d_ws, 0,
                   (size_t)NBATCH * 2 * BPB * SLOT_STRIDE * sizeof(u64), stream);

    fps_kernel<<<NBATCH * BPB, TPB, (size_t)PPB * sizeof(float2), stream>>>(inp, outp, slots);
}

// Round 16
// 56248.474 us; speedup vs baseline: 1.0428x; 1.0428x over previous
//
#include <hip/hip_runtime.h>
#include <stdint.h>

#define NBATCH  32
#define NPTS    131072
#define NPOINTS 4096
#define BPB     16           // blocks per batch -> grid = 512 = 2 blocks/CU (VGPR<=128 pinned)
#define TPB     512          // threads per block
#define PPT     16           // points per thread = NPTS/BPB/TPB
#define PPB     (NPTS / BPB) // 8192

typedef unsigned long long u64;
typedef unsigned int u32;

#define SLOT_STRIDE 8        // u64s -> 64 B between slots

// Slot (batch, parity, block): word0 = [60:49] it+1 | [48:17] f32 dist bits | [16:0] 131071-gi
//                              word1 = (ybits<<32)|xbits   word2 = zbits
// relaxed payload stores -> release tag store; acquire tag poll -> payload loads.
// Parity double-buffer: slot rewritten only 2 steps later (all pollers passed).
//
// Distance (bit-exact vs harness reference, proven r9):
//   d = fma(dz,dz, fma(dx,dx, dy*dy)), dy^2 separately rounded; min-index ties.
//
// r9-r15 lesson: RA *rematerializes* invariant global loads into the loop (pins
// and occupancy attrs don't stop it; dynamic LDS hides occupancy and makes it
// worse). Fix: per-iteration asm volatile "+v" chain on each coord -> the value
// is asm-defined each step, NOT remat-able, loop-carried -> must live in a VGPR.
// Demand ~90 VGPR < 128 budget (waves_per_eu(4,4)) -> no spill incentive.

__global__ __attribute__((amdgpu_flat_work_group_size(TPB, TPB)))
           __attribute__((amdgpu_waves_per_eu(4, 4)))
void fps_kernel(const float* __restrict__ inp, float* __restrict__ out,
                u64* __restrict__ slots)
{
#pragma clang fp contract(off)
    const int bid  = blockIdx.x;
    const int b    = bid & 31;   // batch (all 16 blocks of batch b land on XCD b%8)
    const int j    = bid >> 5;   // block-within-batch 0..15
    const int t    = threadIdx.x;
    const int lane = t & 63;
    const int wid  = t >> 6;

    const float* P  = inp + (size_t)b * NPTS * 3;
    float* outP     = out + (size_t)b * NPOINTS * 3;
    float* outIdx   = out + (size_t)NBATCH * NPOINTS * 3 + (size_t)b * NPOINTS;

    const int base = j * PPB;

    float px[PPT], py[PPT], pz[PPT], dist[PPT];   // 64 data VGPRs
#pragma unroll
    for (int k = 0; k < PPT; ++k) {
        const int p = base + k * TPB + t;
        const float* pp = P + (size_t)p * 3;
        px[k] = pp[0]; py[k] = pp[1]; pz[k] = pp[2];
        dist[k] = 1e10f;
    }

    float qx = P[0], qy = P[1], qz = P[2];   // first selected index is 0
    if (j == 0 && t == 0) {
        outP[0] = qx; outP[1] = qy; outP[2] = qz;
        outIdx[0] = 0.0f;                    // whole d_out read back as float32
    }

    u64* myslots = slots + (size_t)b * (2 * BPB * SLOT_STRIDE);

    __shared__ u64 skey[TPB / 64];
    __shared__ float sq[3];

    for (int it = 0; it < NPOINTS - 1; ++it) {
        // ---- update running min-dist, thread-local argmax (first-max, ascending gi) ----
        float m = -1.0f; int ki = 0;
#pragma unroll
        for (int k = 0; k < PPT; ++k) {
            // loop-carried asm chain: coord is asm-defined every iteration ->
            // RA cannot rematerialize the original load; value stays in a VGPR.
            asm volatile("" : "+v"(px[k]), "+v"(py[k]), "+v"(pz[k]));
            float dx = px[k] - qx;
            float dy = py[k] - qy;
            float dz = pz[k] - qz;
            float yy = dy * dy;
            asm("" : "+v"(yy));                       // dy^2 stays separately rounded
            float d  = __builtin_fmaf(dz, dz,
                        __builtin_fmaf(dx, dx, yy));  // reference contraction shape
            float nd = fminf(dist[k], d);
            dist[k] = nd;
            if (nd > m) { m = nd; ki = k; }           // ascending k => ascending gi
        }
        const int gi = base + ki * TPB + t;
        u64 key = ((u64)__float_as_uint(m) << 17) | (u64)(131071 - gi);

        // ---- wave butterfly reduce (max key) ----
#pragma unroll
        for (int s = 1; s < 64; s <<= 1) {
            u64 o = __shfl_xor(key, s, 64);
            if (o > key) key = o;
        }
        if (lane == 0) skey[wid] = key;
        __syncthreads();

        if (wid == 0) {
            // ---- block reduce over 8 wave keys ----
            u64 k2 = (lane < TPB / 64) ? skey[lane] : 0ull;
            u64 kk = k2;
#pragma unroll
            for (int s = 1; s < TPB / 64; s <<= 1) {
                u64 o = __shfl_xor(kk, s, 64);
                if (o > kk) kk = o;
            }
            const int par = it & 1;
            const u64 tag = (u64)(it + 1) << 49;
            if (lane == 0) {
                // publisher loads its winner's coords once; pollers get them with the poll
                const int bgi = 131071 - (int)(kk & 0x1FFFF);
                const float* qp = P + (size_t)bgi * 3;
                float wx = qp[0], wy = qp[1], wz = qp[2];
                u64* slot = &myslots[(size_t)(par * BPB + j) * SLOT_STRIDE];
                __hip_atomic_store(&slot[1],
                                   ((u64)__float_as_uint(wy) << 32) | __float_as_uint(wx),
                                   __ATOMIC_RELAXED, __HIP_MEMORY_SCOPE_AGENT);
                __hip_atomic_store(&slot[2], (u64)__float_as_uint(wz),
                                   __ATOMIC_RELAXED, __HIP_MEMORY_SCOPE_AGENT);
                __hip_atomic_store(&slot[0], tag | kk,
                                   __ATOMIC_RELEASE, __HIP_MEMORY_SCOPE_AGENT);
            }
            // ---- poll all BPB slots ----
            u64 tw = 0;
            bool ok = (lane >= BPB);
            int guard = 0;
            while (true) {
                if (!ok) {
                    tw = __hip_atomic_load(&myslots[(size_t)(par * BPB + lane) * SLOT_STRIDE],
                                           __ATOMIC_ACQUIRE, __HIP_MEMORY_SCOPE_AGENT);
                    ok = (tw >> 49) >= (u64)(it + 1);
                }
                if (__all((int)ok)) break;
                if (++guard > (1 << 20)) break;   // hang safeguard
            }
            u64 pxy = 0, pzz = 0, k3 = 0;
            if (lane < BPB) {
                u64* slot = &myslots[(size_t)(par * BPB + lane) * SLOT_STRIDE];
                pxy = __hip_atomic_load(&slot[1], __ATOMIC_RELAXED, __HIP_MEMORY_SCOPE_AGENT);
                pzz = __hip_atomic_load(&slot[2], __ATOMIC_RELAXED, __HIP_MEMORY_SCOPE_AGENT);
                k3  = tw & ((1ull << 49) - 1);
            }
            u64 k3m = k3;
#pragma unroll
            for (int s = 1; s < BPB; s <<= 1) {
                u64 o = __shfl_xor(k3m, s, 64);
                if (o > k3m) k3m = o;
            }
            int w3 = __ffsll(__ballot(k3 == k3m && lane < BPB)) - 1;
            u64 wxy = __shfl(pxy, w3, 64);
            u64 wzz = __shfl(pzz, w3, 64);
            if (lane == 0) {
                float nqx = __uint_as_float((u32)wxy);
                float nqy = __uint_as_float((u32)(wxy >> 32));
                float nqz = __uint_as_float((u32)wzz);
                sq[0] = nqx; sq[1] = nqy; sq[2] = nqz;
                if (j == 0) {
                    float* o3 = outP + (size_t)(it + 1) * 3;
                    o3[0] = nqx; o3[1] = nqy; o3[2] = nqz;
                    outIdx[it + 1] = (float)(131071 - (int)(k3m & 0x1FFFF));
                }
            }
        }
        __syncthreads();
        qx = sq[0]; qy = sq[1]; qz = sq[2];
    }
}

extern "C" void kernel_launch(void* const* d_in, const int* in_sizes, int n_in,
                              void* d_out, int out_size, void* d_ws, size_t ws_size,
                              hipStream_t stream)
{
    const float* inp = (const float*)d_in[0];
    float* outp      = (float*)d_out;
    u64* slots       = (u64*)d_ws;

    hipMemsetAsync(d_ws, 0,
                   (size_t)NBATCH * 2 * BPB * SLOT_STRIDE * sizeof(u64), stream);

    fps_kernel<<<NBATCH * BPB, TPB, 0, stream>>>(inp, outp, slots);
}

// Round 17
// 24323.752 us; speedup vs baseline: 2.4116x; 2.3125x over previous
//
#include <hip/hip_runtime.h>
#include <stdint.h>

#define NBATCH  32
#define NPTS    131072
#define NPOINTS 4096
#define BPB     8            // blocks per batch -> grid = 256 = #CUs (1 block/CU, co-resident)
#define TPB     512          // threads per block
#define PPT     32           // points per thread = NPTS/BPB/TPB
#define PPB     (NPTS / BPB) // 16384 points per block

typedef unsigned long long u64;
typedef unsigned int u32;

#define SLOT_STRIDE 8        // u64s -> 64 B between slots

// Slot (batch, parity, block): word0 = [60:49] it+1 | [48:17] f32 dist bits | [16:0] 131071-gi
//                              word1 = (ybits<<32)|xbits   word2 = zbits
// relaxed payload stores -> release tag store; acquire tag poll -> payload loads.
// Parity double-buffer: slot rewritten only 2 steps later (all pollers passed).
//
// Distance (bit-exact vs harness reference, proven r9):
//   d = fma(dz,dz, fma(dx,dx, dy*dy)), dy^2 separately rounded; min-index ties.
//
// Storage plan (r9-r16 lessons):
//  - RA never keeps READ-ONLY arrays resident (remat/sink wins over pins/attrs).
//  - Mutable loop-carried arrays (dist) always survive.
//  - Dynamic LDS hides occupancy from RA; STATIC LDS informs it.
// => x,y in 128 KB STATIC LDS (occupancy ceiling visible: 1 block/CU, 2 waves/SIMD
//    -> pressure heuristics relax); z made loop-carried-mutable via bit-neutral
//    "+ 0.0f" (only feeds dz^2, so -0 -> +0 cannot change any result).

__global__ __attribute__((amdgpu_flat_work_group_size(TPB, TPB)))
void fps_kernel(const float* __restrict__ inp, float* __restrict__ out,
                u64* __restrict__ slots)
{
#pragma clang fp contract(off)
    __shared__ float2 XY[PPB];       // 128 KB static LDS
    __shared__ u64 skey[TPB / 64];
    __shared__ float sq[3];

    const int bid  = blockIdx.x;
    const int b    = bid & 31;   // batch (blocks of batch b all land on XCD b%8)
    const int j    = bid >> 5;   // block-within-batch 0..7
    const int t    = threadIdx.x;
    const int lane = t & 63;
    const int wid  = t >> 6;

    const float* P  = inp + (size_t)b * NPTS * 3;
    float* outP     = out + (size_t)b * NPOINTS * 3;
    float* outIdx   = out + (size_t)NBATCH * NPOINTS * 3 + (size_t)b * NPOINTS;

    const int base = j * PPB;

    float pz[PPT], dist[PPT];    // 64 mutable VGPRs (the class RA keeps resident)
#pragma unroll
    for (int k = 0; k < PPT; ++k) {
        const int l = k * TPB + t;
        const float* pp = P + (size_t)(base + l) * 3;
        float x = pp[0], y = pp[1], z = pp[2];
        XY[l] = make_float2(x, y);
        pz[k] = z;
        dist[k] = 1e10f;
    }

    float qx = P[0], qy = P[1], qz = P[2];   // first selected index is 0
    if (j == 0 && t == 0) {
        outP[0] = qx; outP[1] = qy; outP[2] = qz;
        outIdx[0] = 0.0f;                    // whole d_out read back as float32
    }

    u64* myslots = slots + (size_t)b * (2 * BPB * SLOT_STRIDE);

    __syncthreads();   // XY visible to all waves

    for (int it = 0; it < NPOINTS - 1; ++it) {
        // ---- update running min-dist, thread-local argmax (first-max, ascending gi) ----
        float m = -1.0f; int ki = 0;
#pragma unroll
        for (int k = 0; k < PPT; ++k) {
            float2 xy = XY[k * TPB + t];              // ds_read_b64, 2-way bank alias (free)
            float dx = xy.x - qx;
            float dy = xy.y - qy;
            float dz = pz[k] - qz;
            float yy = dy * dy;
            asm("" : "+v"(yy));                       // dy^2 stays separately rounded
            float d  = __builtin_fmaf(dz, dz,
                        __builtin_fmaf(dx, dx, yy));  // reference contraction shape
            float nd = fminf(dist[k], d);
            dist[k] = nd;
            if (nd > m) { m = nd; ki = k; }           // ascending k => ascending gi
            pz[k] = pz[k] + 0.0f;  // bit-neutral mutation: pz is loop-carried ->
                                   // RA must keep it resident (cannot remat/sink)
        }
        const int gi = base + ki * TPB + t;
        u64 key = ((u64)__float_as_uint(m) << 17) | (u64)(131071 - gi);

        // ---- wave butterfly reduce (max key) ----
#pragma unroll
        for (int s = 1; s < 64; s <<= 1) {
            u64 o = __shfl_xor(key, s, 64);
            if (o > key) key = o;
        }
        if (lane == 0) skey[wid] = key;
        __syncthreads();

        if (wid == 0) {
            // ---- block reduce over 8 wave keys ----
            u64 k2 = (lane < TPB / 64) ? skey[lane] : 0ull;
            u64 kk = k2;
#pragma unroll
            for (int s = 1; s < TPB / 64; s <<= 1) {
                u64 o = __shfl_xor(kk, s, 64);
                if (o > kk) kk = o;
            }
            const int par = it & 1;
            const u64 tag = (u64)(it + 1) << 49;
            if (lane == 0) {
                // publisher loads its winner's coords once; pollers get them with the poll
                const int bgi = 131071 - (int)(kk & 0x1FFFF);
                const float* qp = P + (size_t)bgi * 3;
                float wx = qp[0], wy = qp[1], wz = qp[2];
                u64* slot = &myslots[(size_t)(par * BPB + j) * SLOT_STRIDE];
                __hip_atomic_store(&slot[1],
                                   ((u64)__float_as_uint(wy) << 32) | __float_as_uint(wx),
                                   __ATOMIC_RELAXED, __HIP_MEMORY_SCOPE_AGENT);
                __hip_atomic_store(&slot[2], (u64)__float_as_uint(wz),
                                   __ATOMIC_RELAXED, __HIP_MEMORY_SCOPE_AGENT);
                __hip_atomic_store(&slot[0], tag | kk,
                                   __ATOMIC_RELEASE, __HIP_MEMORY_SCOPE_AGENT);
            }
            // ---- poll all BPB slots ----
            u64 tw = 0;
            bool ok = (lane >= BPB);
            int guard = 0;
            while (true) {
                if (!ok) {
                    tw = __hip_atomic_load(&myslots[(size_t)(par * BPB + lane) * SLOT_STRIDE],
                                           __ATOMIC_ACQUIRE, __HIP_MEMORY_SCOPE_AGENT);
                    ok = (tw >> 49) >= (u64)(it + 1);
                }
                if (__all((int)ok)) break;
                if (++guard > (1 << 20)) break;   // hang safeguard (unreachable when co-resident)
            }
            u64 pxy = 0, pzz = 0, k3 = 0;
            if (lane < BPB) {
                u64* slot = &myslots[(size_t)(par * BPB + lane) * SLOT_STRIDE];
                pxy = __hip_atomic_load(&slot[1], __ATOMIC_RELAXED, __HIP_MEMORY_SCOPE_AGENT);
                pzz = __hip_atomic_load(&slot[2], __ATOMIC_RELAXED, __HIP_MEMORY_SCOPE_AGENT);
                k3  = tw & ((1ull << 49) - 1);
            }
            u64 k3m = k3;
#pragma unroll
            for (int s = 1; s < BPB; s <<= 1) {
                u64 o = __shfl_xor(k3m, s, 64);
                if (o > k3m) k3m = o;
            }
            int w3 = __ffsll(__ballot(k3 == k3m && lane < BPB)) - 1;
            u64 wxy = __shfl(pxy, w3, 64);
            u64 wzz = __shfl(pzz, w3, 64);
            if (lane == 0) {
                float nqx = __uint_as_float((u32)wxy);
                float nqy = __uint_as_float((u32)(wxy >> 32));
                float nqz = __uint_as_float((u32)wzz);
                sq[0] = nqx; sq[1] = nqy; sq[2] = nqz;
                if (j == 0) {
                    float* o3 = outP + (size_t)(it + 1) * 3;
                    o3[0] = nqx; o3[1] = nqy; o3[2] = nqz;
                    outIdx[it + 1] = (float)(131071 - (int)(k3m & 0x1FFFF));
                }
            }
        }
        __syncthreads();
        qx = sq[0]; qy = sq[1]; qz = sq[2];
    }
}

extern "C" void kernel_launch(void* const* d_in, const int* in_sizes, int n_in,
                              void* d_out, int out_size, void* d_ws, size_t ws_size,
                              hipStream_t stream)
{
    const float* inp = (const float*)d_in[0];
    float* outp      = (float*)d_out;
    u64* slots       = (u64*)d_ws;

    hipMemsetAsync(d_ws, 0,
                   (size_t)NBATCH * 2 * BPB * SLOT_STRIDE * sizeof(u64), stream);

    fps_kernel<<<NBATCH * BPB, TPB, 0, stream>>>(inp, outp, slots);
}